// Round 8
// baseline (287.450 us; speedup 1.0000x reference)
//
#include <hip/hip_runtime.h>
#include <math.h>

typedef _Float16 half8   __attribute__((ext_vector_type(8)));
typedef _Float16 half4_t __attribute__((ext_vector_type(4)));
typedef _Float16 half2_t __attribute__((ext_vector_type(2)));
typedef float    floatx4 __attribute__((ext_vector_type(4)));
typedef unsigned int uint4_t __attribute__((ext_vector_type(4)));

namespace {

constexpr int S  = 2048;
constexpr int D  = 64;
constexpr int BH = 32;
constexpr int QT = 64;
constexpr float INV_T = 0.125f;
constexpr size_t PLANE = (size_t)BH * S * D;
constexpr float MBIAS = 2.772588722239781f;   // 4*ln2 (cancels in O/l)

#define MFMA16(a, b, c) __builtin_amdgcn_mfma_f32_16x16x32_f16((a), (b), (c), 0, 0, 0)

typedef __attribute__((address_space(1))) const unsigned int guint;
typedef __attribute__((address_space(3))) unsigned int luint;

__device__ __forceinline__ void gl_lds16(const _Float16* g, _Float16* l) {
    __builtin_amdgcn_global_load_lds((guint*)g, (luint*)l, 16, 0, 0);
}

// pack two f32 -> one dword of two f16 (RTZ)
__device__ __forceinline__ unsigned pk2(float a, float b) {
#if __has_builtin(__builtin_amdgcn_cvt_pkrtz)
    auto h = __builtin_amdgcn_cvt_pkrtz(a, b);
    return __builtin_bit_cast(unsigned, h);
#else
    half2_t h = {(_Float16)a, (_Float16)b};
    return __builtin_bit_cast(unsigned, h);
#endif
}

// v_permlane32_swap_b32: a[32+i] <-> b[i]  (i=0..31)
__device__ __forceinline__ void pl32swap(unsigned &a, unsigned &b) {
    asm("v_permlane32_swap_b32 %0, %1" : "+v"(a), "+v"(b));
}
// v_permlane16_swap_b32: a[16+i] <-> b[i] within each 32-lane half
__device__ __forceinline__ void pl16swap(unsigned &a, unsigned &b) {
    asm("v_permlane16_swap_b32 %0, %1" : "+v"(a), "+v"(b));
}

// In-register 16x32 P transpose across the g-quad {m, m+16, m+32, m+48}.
// Inputs: A0=pk(t=4g,4g+1) A1=pk(4g+2,4g+3) of nt0; B0,B1 same of nt1 (t+16).
// Output: half8 A-fragment = t in [8g, 8g+8) at q=m.
__device__ __forceinline__ half8 xpose4(unsigned A0, unsigned A1,
                                        unsigned B0, unsigned B1) {
    pl32swap(A0, B0);            // A0 -> X0, B0 -> Y0
    pl32swap(A1, B1);
    pl16swap(A0, B0);            // X0,Y0 -> D0,D2
    pl16swap(A1, B1);            // X1,Y1 -> D1,D3
    uint4_t d = (uint4_t){A0, A1, B0, B1};
    return __builtin_bit_cast(half8, d);
}

// ---- fast pre-pass (layouts bit-equivalent to the verified R4 prep):
// K planes: out[(bh*S+t)*64 + p*8 + e] = f16( K[bh][t][(p^(t&7))*8 + e] )
// V planes: out[(bh*64+d)*S + w*64 + p*8 + e] =
//             f16( V[bh][ w*64 + ((p&4)|((p&3)^(d&3)))*8 + e ][ d ] )
__global__ __launch_bounds__(256)
void prep_all2(const float* __restrict__ kr, const float* __restrict__ ki,
               const float* __restrict__ vr, const float* __restrict__ vi,
               _Float16* __restrict__ okr, _Float16* __restrict__ oki,
               _Float16* __restrict__ ovr, _Float16* __restrict__ ovi)
{
    const int tid = (int)threadIdx.x;
    const int b   = (int)blockIdx.x;

    if (b < 2048) {
        // ---- K: one 16B output chunk per thread, both planes ----
        const int idx = b * 256 + tid;          // 0 .. 524287
        const int R   = idx >> 3, p = idx & 7;  // R = bh*S + t ; t&7 == R&7
        const int key = R & 7;
        const size_t in = (size_t)R * 64 + (size_t)((p ^ key) * 8);
        const size_t ot = (size_t)idx * 8;
        float4 a0 = *(const float4*)(kr + in);
        float4 a1 = *(const float4*)(kr + in + 4);
        float4 c0 = *(const float4*)(ki + in);
        float4 c1 = *(const float4*)(ki + in + 4);
        uint4_t ha = (uint4_t){pk2(a0.x,a0.y), pk2(a0.z,a0.w),
                               pk2(a1.x,a1.y), pk2(a1.z,a1.w)};
        uint4_t hc = (uint4_t){pk2(c0.x,c0.y), pk2(c0.z,c0.w),
                               pk2(c1.x,c1.y), pk2(c1.z,c1.w)};
        *(uint4_t*)(okr + ot) = ha;
        *(uint4_t*)(oki + ot) = hc;
    } else {
        // ---- V: 8x8 in-register transpose; block = (bh, z, 256-row t-span) ----
        const int b2   = b - 2048;              // 0..511
        const int bh   = b2 >> 4;
        const int rest = b2 & 15;
        const int z    = rest >> 3, Tb = rest & 7;
        const int T    = Tb * 256;
        const float* src = z ? vi : vr;
        _Float16*    dst = z ? ovi : ovr;

        const int tq = tid & 31, dq = tid >> 5;   // 32 t-chunks x 8 d-chunks
        const int t0 = T + tq * 8, d0 = dq * 8;

        float v[8][8];
        #pragma unroll
        for (int i = 0; i < 8; ++i) {
            const size_t in = ((size_t)bh * S + t0 + i) * 64 + d0;
            float4 lo = *(const float4*)(src + in);
            float4 hi = *(const float4*)(src + in + 4);
            v[i][0]=lo.x; v[i][1]=lo.y; v[i][2]=lo.z; v[i][3]=lo.w;
            v[i][4]=hi.x; v[i][5]=hi.y; v[i][6]=hi.z; v[i][7]=hi.w;
        }

        const int jd = tq & 7;                    // data chunk within 64-window
        const size_t rowoff = (size_t)T + (size_t)(tq >> 3) * 64;  // window base
        #pragma unroll
        for (int j = 0; j < 8; ++j) {
            const int d   = d0 + j;               // d&3 == j&3 (d0 % 8 == 0)
            const int pos = (jd & 4) | ((jd & 3) ^ (j & 3));
            uint4_t h = (uint4_t){pk2(v[0][j], v[1][j]), pk2(v[2][j], v[3][j]),
                                  pk2(v[4][j], v[5][j]), pk2(v[6][j], v[7][j])};
            *(uint4_t*)(dst + ((size_t)bh * 64 + d) * S + rowoff + pos * 8) = h;
        }
    }
}

// ---- main: 16x16x32 MFMA flash complex attention ----
// NEW (R8): 3-buffer pipeline with counted vmcnt — loads stay in flight
// across barriers (T3/T4). Per tile: vmcnt(4) [my tile-kt loads landed,
// tile-kt+1's 4 stay in flight] -> raw s_barrier [all waves' tile-kt data
// visible; orders prev compute for WAR] -> stage(kt+2) -> compute(kt).
// Compute/routing byte-identical to R7. Softmax stays SCALAR (R2/R3/R6
// lesson: every packed variant fails structurally).
__global__ __launch_bounds__(256, 3)
void cv_attn_db(const float* __restrict__ qr_g, const float* __restrict__ qi_g,
                const _Float16* __restrict__ kh_r, const _Float16* __restrict__ kh_i,
                const _Float16* __restrict__ vt_r, const _Float16* __restrict__ vt_i,
                float* __restrict__ out)
{
    // 3 bufs x 4 planes x 2048 halves = 49152 B -> 3 blocks/CU
    __shared__ __align__(16) _Float16 sm[3*4*2048];

    const int tid = (int)threadIdx.x, lane = tid & 63, wv = tid >> 6;
    const int g = lane >> 4, m = lane & 15;
    // phi(m): swap bit0 <-> bit2 (involution). Used for V row slot placement.
    const int fm = (m & 10) | ((m & 1) << 2) | ((m >> 2) & 1);

    // XCD-aware decode: one bh per XCD slice (f16 K/V ~1MB/bh stays L2-local)
    const int b   = (int)blockIdx.x;
    const int xcd = b & 7, y = b >> 3;
    const int qt  = y & 31, bh = xcd + 8 * (y >> 5);
    const int q0  = qt * QT;
    const size_t base = (size_t)bh * S * D;

    // ---- Q fragments (row=m, k=g*8+j + kc*32), scaled by 1/T; Qi negated once ----
    half8 aqr[2], aqi[2], aqin[2];
    {
        const size_t qoff = base + (size_t)(q0 + wv*16 + m) * D + g*8;
        #pragma unroll
        for (int kc = 0; kc < 2; ++kc) {
            float4 r0 = *(const float4*)(qr_g + qoff + kc*32);
            float4 r1 = *(const float4*)(qr_g + qoff + kc*32 + 4);
            float4 i0 = *(const float4*)(qi_g + qoff + kc*32);
            float4 i1 = *(const float4*)(qi_g + qoff + kc*32 + 4);
            half8 hr, hi;
            hr[0]=(_Float16)(r0.x*INV_T); hr[1]=(_Float16)(r0.y*INV_T);
            hr[2]=(_Float16)(r0.z*INV_T); hr[3]=(_Float16)(r0.w*INV_T);
            hr[4]=(_Float16)(r1.x*INV_T); hr[5]=(_Float16)(r1.y*INV_T);
            hr[6]=(_Float16)(r1.z*INV_T); hr[7]=(_Float16)(r1.w*INV_T);
            hi[0]=(_Float16)(i0.x*INV_T); hi[1]=(_Float16)(i0.y*INV_T);
            hi[2]=(_Float16)(i0.z*INV_T); hi[3]=(_Float16)(i0.w*INV_T);
            hi[4]=(_Float16)(i1.x*INV_T); hi[5]=(_Float16)(i1.y*INV_T);
            hi[6]=(_Float16)(i1.z*INV_T); hi[7]=(_Float16)(i1.w*INV_T);
            aqr[kc] = hr; aqi[kc] = hi; aqin[kc] = -hi;
        }
    }

    floatx4 Or[4], Oi[4];
    float l_run = 0.f;                       // l for q=m (lane-local under swapped QK^T)
    #pragma unroll
    for (int nt = 0; nt < 4; ++nt) {
        Or[nt] = (floatx4){0.f,0.f,0.f,0.f};
        Oi[nt] = (floatx4){0.f,0.f,0.f,0.f};
    }

    // ---- per-wave staging bases, hoisted (branchless stage) ----
    const int dl  = lane >> 2;
    const int fdl = (dl & 10) | ((dl & 1) << 2) | ((dl >> 2) & 1);  // phi
    const _Float16* const stage_src =
        (wv == 0) ? kh_r + (size_t)bh*S*D + lane*8 :
        (wv == 1) ? kh_i + (size_t)bh*S*D + lane*8 :
        (wv == 2) ? vt_r + ((size_t)bh*D + fdl)*S + (lane&3)*8
                  : vt_i + ((size_t)bh*D + fdl)*S + (lane&3)*8;
    const size_t kstep   = (wv < 2) ? (size_t)(32*D) : 32;
    const size_t istride = (wv < 2) ? 512 : (size_t)16*S;
    _Float16* const stage_dst0 = sm + wv*2048;

    auto stage = [&](int kt, int bsel) {
        const _Float16* s = stage_src + (size_t)kt * kstep;
        _Float16* d = stage_dst0 + bsel * 8192;
        #pragma unroll
        for (int i = 0; i < 4; ++i)
            gl_lds16(s + i*istride, d + i*512);
    };

    // ---- hoisted compute constants ----
    const int kck0 = (g ^ (m & 7)) * 8, kck1 = ((g + 4) ^ (m & 7)) * 8;
    const int vck  = (g ^ (m & 3)) * 8;
    const int vrb0 = fm * 32;
    const int m64  = m * 64;

    auto compute = [&](const _Float16* bs) {
        const _Float16* const Krt = bs;
        const _Float16* const Kit = bs + 2048;
        const _Float16* const Vrt = bs + 4096;
        const _Float16* const Vit = bs + 6144;

        // ---- scores, swapped: Z^T block nt -> lane holds t = 16nt+4g+r, q = m ----
        floatx4 Zr[2], Zi[2];
        __builtin_amdgcn_s_setprio(1);
        #pragma unroll
        for (int nt = 0; nt < 2; ++nt) {
            const int rb = nt*1024 + m64;
            half8 bkr0 = *(const half8*)&Krt[rb + kck0];
            half8 bki0 = *(const half8*)&Kit[rb + kck0];
            half8 bkr1 = *(const half8*)&Krt[rb + kck1];
            half8 bki1 = *(const half8*)&Kit[rb + kck1];
            floatx4 zr = (floatx4){0.f,0.f,0.f,0.f};
            floatx4 zi = (floatx4){0.f,0.f,0.f,0.f};
            zr = MFMA16(bkr0, aqr[0],  zr);
            zr = MFMA16(bki0, aqin[0], zr);
            zr = MFMA16(bkr1, aqr[1],  zr);
            zr = MFMA16(bki1, aqin[1], zr);    // Zr^T = Kr Qr' - Ki Qi'
            zi = MFMA16(bki0, aqr[0],  zi);
            zi = MFMA16(bkr0, aqi[0],  zi);
            zi = MFMA16(bki1, aqr[1],  zi);
            zi = MFMA16(bkr1, aqi[1],  zi);    // Zi^T = Ki Qr' + Kr Qi'
            Zr[nt] = zr; Zi[nt] = zi;
        }
        __builtin_amdgcn_s_setprio(0);

        // ---- max-free softmax: p = exp(|z|)*2^-4; P = p*z/|z| (SCALAR form) ----
        unsigned PkR[4], PkI[4];   // chunk c = nt*2 + pair: pk(t pair) at group g
        #pragma unroll
        for (int nt = 0; nt < 2; ++nt) {
            float wr[4], wi[4];
            #pragma unroll
            for (int r = 0; r < 4; ++r) {
                const float zr = Zr[nt][r], zi = Zi[nt][r];
                const float s2  = fmaf(zr, zr, fmaf(zi, zi, 1e-24f));
                const float inv = __builtin_amdgcn_rsqf(s2);
                const float mag = s2 * inv;
                const float p   = __expf(mag - MBIAS);
                l_run += p;
                const float w = p * inv;
                wr[r] = w * zr; wi[r] = w * zi;
            }
            PkR[nt*2 + 0] = pk2(wr[0], wr[1]);
            PkR[nt*2 + 1] = pk2(wr[2], wr[3]);
            PkI[nt*2 + 0] = pk2(wi[0], wi[1]);
            PkI[nt*2 + 1] = pk2(wi[2], wi[3]);
        }

        // ---- in-register P transpose: A-fragment (q=m, t=8g..8g+7) per plane ----
        half8 apr = xpose4(PkR[0], PkR[1], PkR[2], PkR[3]);
        half8 api = xpose4(PkI[0], PkI[1], PkI[2], PkI[3]);
        half8 nai = -api;

        // ---- PV: O += P * V. Row nt*16+m lives at slot nt*16+phi(m);
        // ---- chunk key (g ^ (m&3)) -> routing identical to R1.
        __builtin_amdgcn_s_setprio(1);
        #pragma unroll
        for (int nt = 0; nt < 4; ++nt) {
            const int vrb = nt*512 + vrb0;
            half8 bvr = *(const half8*)&Vrt[vrb + vck];
            half8 bvi = *(const half8*)&Vit[vrb + vck];
            Or[nt] = MFMA16(apr, bvr, Or[nt]);
            Or[nt] = MFMA16(nai, bvi, Or[nt]);
            Oi[nt] = MFMA16(apr, bvi, Oi[nt]);
            Oi[nt] = MFMA16(api, bvr, Oi[nt]);
        }
        __builtin_amdgcn_s_setprio(0);
    };

    // ---- pipelined K-loop: counted vmcnt, loads span barriers ----
    // Pin the vmcnt accounting: drain Q loads so only stage loads are counted.
    asm volatile("s_waitcnt vmcnt(0)" ::: "memory");
    stage(0, 0);
    stage(1, 1);                        // 8 loads outstanding per wave
    int cb = 0;                         // buffer holding tile kt
    for (int kt = 0; kt < 64; ++kt) {
        // my tile-kt loads (oldest 4) landed; tile-kt+1's 4 stay in flight
        asm volatile("s_waitcnt vmcnt(4)" ::: "memory");
        __builtin_amdgcn_s_barrier();   // all waves' tile-kt data in LDS; prev compute done
        const int sb = (cb >= 1) ? cb - 1 : cb + 2;     // (cb+2)%3 != cb, != cb+1
        stage((kt + 2) & 63, sb);       // tail wraps: tiles 0,1 into dead buffers, never read
        compute(sm + cb * 8192);
        cb = (cb == 2) ? 0 : cb + 1;
    }

    // ---- deferred l reduction: sum over the g-quad (each lane has 8 t's per tile) ----
    l_run += __shfl_xor(l_run, 16, 64);
    l_run += __shfl_xor(l_run, 32, 64);
    // lane quad {m,m+16,m+32,m+48} now holds l(q=m); gather l(q=4g+r) for output rows

    #pragma unroll
    for (int r = 0; r < 4; ++r) {
        const float linv = 1.0f / __shfl(l_run, 4*g + r, 64);
        const size_t o = base + (size_t)(q0 + wv*16 + 4*g + r) * D + m;
        #pragma unroll
        for (int nt = 0; nt < 4; ++nt) {
            out[o + nt*16]         = Or[nt][r] * linv;
            out[PLANE + o + nt*16] = Oi[nt][r] * linv;
        }
    }
}

// ---------------- fallback (ws too small): round-2 style, f32 inputs ----------------
constexpr int ST2 = 72;
__global__ __launch_bounds__(256, 2)
void cv_attn_mfma(const float* __restrict__ qr_g, const float* __restrict__ qi_g,
                  const float* __restrict__ kr_g, const float* __restrict__ ki_g,
                  const float* __restrict__ vr_g, const float* __restrict__ vi_g,
                  float* __restrict__ out)
{
    __shared__ __align__(16) _Float16 sm[4*64*ST2 + 4*2*16*ST2];
    _Float16* const Kr = sm;
    _Float16* const Ki = Kr + 64*ST2;
    _Float16* const Vr = Ki + 64*ST2;
    _Float16* const Vi = Vr + 64*ST2;
    _Float16* const Pb = Vi + 64*ST2;

    const int tid = (int)threadIdx.x, lane = tid & 63, wv = tid >> 6;
    const int g = lane >> 4, m = lane & 15;
    const int bh = (int)blockIdx.y;
    const int q0 = (int)blockIdx.x * QT;
    const size_t base = (size_t)bh * S * D;
    _Float16* const Pr = Pb + wv * (2*16*ST2);
    _Float16* const Pi = Pr + 16*ST2;
    const int lofs = m*ST2 + g*8;

    half8 aqr[2], aqi[2], aqin[2];
    {
        const size_t qoff = base + (size_t)(q0 + wv*16 + m) * D + g*8;
        #pragma unroll
        for (int kc = 0; kc < 2; ++kc) {
            float4 r0 = *(const float4*)(qr_g + qoff + kc*32);
            float4 r1 = *(const float4*)(qr_g + qoff + kc*32 + 4);
            float4 i0 = *(const float4*)(qi_g + qoff + kc*32);
            float4 i1 = *(const float4*)(qi_g + qoff + kc*32 + 4);
            half8 hr, hi;
            hr[0]=(_Float16)(r0.x*INV_T); hr[1]=(_Float16)(r0.y*INV_T);
            hr[2]=(_Float16)(r0.z*INV_T); hr[3]=(_Float16)(r0.w*INV_T);
            hr[4]=(_Float16)(r1.x*INV_T); hr[5]=(_Float16)(r1.y*INV_T);
            hr[6]=(_Float16)(r1.z*INV_T); hr[7]=(_Float16)(r1.w*INV_T);
            hi[0]=(_Float16)(i0.x*INV_T); hi[1]=(_Float16)(i0.y*INV_T);
            hi[2]=(_Float16)(i0.z*INV_T); hi[3]=(_Float16)(i0.w*INV_T);
            hi[4]=(_Float16)(i1.x*INV_T); hi[5]=(_Float16)(i1.y*INV_T);
            hi[6]=(_Float16)(i1.z*INV_T); hi[7]=(_Float16)(i1.w*INV_T);
            aqr[kc] = hr; aqi[kc] = hi; aqin[kc] = -hi;
        }
    }

    floatx4 Or[4], Oi[4];
    float m_run[4], l_run[4];
    #pragma unroll
    for (int r = 0; r < 4; ++r) { m_run[r] = -INFINITY; l_run[r] = 0.f; }
    #pragma unroll
    for (int nt = 0; nt < 4; ++nt) {
        Or[nt] = (floatx4){0.f,0.f,0.f,0.f};
        Oi[nt] = (floatx4){0.f,0.f,0.f,0.f};
    }

    for (int kt = 0; kt < S/64; ++kt) {
        const int k0 = kt * 64;
        __syncthreads();
        if (wv < 2) {
            const float* src = (wv == 0 ? kr_g : ki_g) + base + (size_t)k0 * D;
            _Float16* dst = (wv == 0 ? Kr : Ki);
            #pragma unroll
            for (int it = 0; it < 16; ++it) {
                const int e = it*64 + lane, t = e >> 4, c4 = (e & 15) * 4;
                float4 v = *(const float4*)(src + t*64 + c4);
                half4_t hh = {(_Float16)v.x, (_Float16)v.y, (_Float16)v.z, (_Float16)v.w};
                *(half4_t*)&dst[t*ST2 + c4] = hh;
            }
        } else {
            const float* src = (wv == 2 ? vr_g : vi_g) + base + (size_t)k0 * D;
            _Float16* dst = (wv == 2 ? Vr : Vi);
            #pragma unroll
            for (int t0 = 0; t0 < 64; t0 += 4) {
                float v0 = src[(t0+0)*64 + lane];
                float v1 = src[(t0+1)*64 + lane];
                float v2 = src[(t0+2)*64 + lane];
                float v3 = src[(t0+3)*64 + lane];
                half4_t hh = {(_Float16)v0, (_Float16)v1, (_Float16)v2, (_Float16)v3};
                *(half4_t*)&dst[lane*ST2 + t0] = hh;
            }
        }
        __syncthreads();

        floatx4 Zr[4], Zi[4];
        #pragma unroll
        for (int nt = 0; nt < 4; ++nt) {
            floatx4 zr = (floatx4){0.f,0.f,0.f,0.f};
            floatx4 zi = (floatx4){0.f,0.f,0.f,0.f};
            #pragma unroll
            for (int kc = 0; kc < 2; ++kc) {
                const int o = nt*16*ST2 + lofs + kc*32;
                half8 bkr = *(const half8*)&Kr[o];
                half8 bki = *(const half8*)&Ki[o];
                zr = MFMA16(aqr[kc],  bkr, zr);
                zr = MFMA16(aqin[kc], bki, zr);
                zi = MFMA16(aqr[kc],  bki, zi);
                zi = MFMA16(aqi[kc],  bkr, zi);
            }
            Zr[nt] = zr; Zi[nt] = zi;
        }

        float mag[4][4], mt[4] = {0.f,0.f,0.f,0.f};
        #pragma unroll
        for (int nt = 0; nt < 4; ++nt)
            #pragma unroll
            for (int r = 0; r < 4; ++r) {
                const float a = Zr[nt][r], bz = Zi[nt][r];
                const float s = __builtin_amdgcn_sqrtf(a*a + bz*bz);
                mag[nt][r] = s; mt[r] = fmaxf(mt[r], s);
            }
        #pragma unroll
        for (int off = 1; off < 16; off <<= 1)
            #pragma unroll
            for (int r = 0; r < 4; ++r)
                mt[r] = fmaxf(mt[r], __shfl_xor(mt[r], off, 64));

        float alpha[4], rs[4];
        #pragma unroll
        for (int r = 0; r < 4; ++r) {
            const float mnew = fmaxf(m_run[r], mt[r]);
            alpha[r] = __expf(m_run[r] - mnew);
            m_run[r] = mnew; rs[r] = 0.f;
        }
        #pragma unroll
        for (int nt = 0; nt < 4; ++nt)
            #pragma unroll
            for (int r = 0; r < 4; ++r) {
                const float p = __expf(mag[nt][r] - m_run[r]);
                rs[r] += p;
                const float w = p * __builtin_amdgcn_rcpf(fmaxf(mag[nt][r], 1e-12f));
                Pr[(4*g + r)*ST2 + nt*16 + m] = (_Float16)(w * Zr[nt][r]);
                Pi[(4*g + r)*ST2 + nt*16 + m] = (_Float16)(w * Zi[nt][r]);
            }
        #pragma unroll
        for (int off = 1; off < 16; off <<= 1)
            #pragma unroll
            for (int r = 0; r < 4; ++r)
                rs[r] += __shfl_xor(rs[r], off, 64);
        #pragma unroll
        for (int r = 0; r < 4; ++r) l_run[r] = l_run[r]*alpha[r] + rs[r];

        #pragma unroll
        for (int nt = 0; nt < 4; ++nt)
            #pragma unroll
            for (int r = 0; r < 4; ++r) { Or[nt][r] *= alpha[r]; Oi[nt][r] *= alpha[r]; }

        half8 apr[2], api[2], apin[2];
        #pragma unroll
        for (int kc = 0; kc < 2; ++kc) {
            apr[kc]  = *(const half8*)&Pr[lofs + kc*32];
            api[kc]  = *(const half8*)&Pi[lofs + kc*32];
            apin[kc] = -api[kc];
        }
        #pragma unroll
        for (int nt = 0; nt < 4; ++nt) {
            floatx4 ors = Or[nt], ois = Oi[nt];
            #pragma unroll
            for (int kc = 0; kc < 2; ++kc) {
                const int o = nt*16*ST2 + lofs + kc*32;
                half8 bvr = *(const half8*)&Vr[o];
                half8 bvi = *(const half8*)&Vi[o];
                ors = MFMA16(apr[kc],  bvr, ors);
                ors = MFMA16(apin[kc], bvi, ors);
                ois = MFMA16(apr[kc],  bvi, ois);
                ois = MFMA16(api[kc],  bvr, ois);
            }
            Or[nt] = ors; Oi[nt] = ois;
        }
    }

    #pragma unroll
    for (int r = 0; r < 4; ++r) {
        const float linv = 1.0f / l_run[r];
        const size_t o = base + (size_t)(q0 + wv*16 + 4*g + r) * D + m;
        #pragma unroll
        for (int nt = 0; nt < 4; ++nt) {
            out[o + nt*16]         = Or[nt][r] * linv;
            out[PLANE + o + nt*16] = Oi[nt][r] * linv;
        }
    }
}

} // namespace

extern "C" void kernel_launch(void* const* d_in, const int* in_sizes, int n_in,
                              void* d_out, int out_size, void* d_ws, size_t ws_size,
                              hipStream_t stream) {
    const float* qr = (const float*)d_in[0];
    const float* qi = (const float*)d_in[1];
    const float* kr = (const float*)d_in[2];
    const float* ki = (const float*)d_in[3];
    const float* vr = (const float*)d_in[4];
    const float* vi = (const float*)d_in[5];
    float* out = (float*)d_out;

    const size_t PH = (size_t)BH * S * D;            // halves per ws plane
    const size_t need = 4 * PH * sizeof(_Float16);   // 33.6 MB
    if (ws_size >= need) {
        _Float16* khr = (_Float16*)d_ws;
        _Float16* khi = khr + PH;
        _Float16* vtr = khi + PH;
        _Float16* vti = vtr + PH;
        prep_all2<<<2560, 256, 0, stream>>>(kr, ki, vr, vi, khr, khi, vtr, vti);
        cv_attn_db<<<1024, 256, 0, stream>>>(qr, qi, khr, khi, vtr, vti, out);
    } else {
        cv_attn_mfma<<<dim3(32, 32), 256, 0, stream>>>(qr, qi, kr, ki, vr, vi, out);
    }
}

// Round 10
// 278.628 us; speedup vs baseline: 1.0317x; 1.0317x over previous
//
#include <hip/hip_runtime.h>
#include <math.h>

typedef _Float16 half8   __attribute__((ext_vector_type(8)));
typedef _Float16 half4_t __attribute__((ext_vector_type(4)));
typedef _Float16 half2_t __attribute__((ext_vector_type(2)));
typedef float    floatx4 __attribute__((ext_vector_type(4)));
typedef unsigned int uint4_t __attribute__((ext_vector_type(4)));

namespace {

constexpr int S  = 2048;
constexpr int D  = 64;
constexpr int BH = 32;
constexpr int QT = 128;                 // 128 q-rows per block (8 waves)
constexpr float INV_T = 0.125f;
constexpr size_t PLANE = (size_t)BH * S * D;
constexpr float MBIAS = 2.772588722239781f;   // 4*ln2 (cancels in O/l)

#define MFMA16(a, b, c) __builtin_amdgcn_mfma_f32_16x16x32_f16((a), (b), (c), 0, 0, 0)

typedef __attribute__((address_space(1))) const unsigned int guint;
typedef __attribute__((address_space(3))) unsigned int luint;

__device__ __forceinline__ void gl_lds16(const _Float16* g, _Float16* l) {
    __builtin_amdgcn_global_load_lds((guint*)g, (luint*)l, 16, 0, 0);
}

// pack two f32 -> one dword of two f16 (RTZ)
__device__ __forceinline__ unsigned pk2(float a, float b) {
#if __has_builtin(__builtin_amdgcn_cvt_pkrtz)
    auto h = __builtin_amdgcn_cvt_pkrtz(a, b);
    return __builtin_bit_cast(unsigned, h);
#else
    half2_t h = {(_Float16)a, (_Float16)b};
    return __builtin_bit_cast(unsigned, h);
#endif
}

// v_permlane32_swap_b32: a[32+i] <-> b[i]  (i=0..31)
__device__ __forceinline__ void pl32swap(unsigned &a, unsigned &b) {
    asm("v_permlane32_swap_b32 %0, %1" : "+v"(a), "+v"(b));
}
// v_permlane16_swap_b32: a[16+i] <-> b[i] within each 32-lane half
__device__ __forceinline__ void pl16swap(unsigned &a, unsigned &b) {
    asm("v_permlane16_swap_b32 %0, %1" : "+v"(a), "+v"(b));
}

// In-register 16x32 P transpose across the g-quad {m, m+16, m+32, m+48}.
// Inputs: A0=pk(t=4g,4g+1) A1=pk(4g+2,4g+3) of nt0; B0,B1 same of nt1 (t+16).
// Output: half8 A-fragment = t in [8g, 8g+8) at q=m.
__device__ __forceinline__ half8 xpose4(unsigned A0, unsigned A1,
                                        unsigned B0, unsigned B1) {
    pl32swap(A0, B0);            // A0 -> X0, B0 -> Y0
    pl32swap(A1, B1);
    pl16swap(A0, B0);            // X0,Y0 -> D0,D2
    pl16swap(A1, B1);            // X1,Y1 -> D1,D3
    uint4_t d = (uint4_t){A0, A1, B0, B1};
    return __builtin_bit_cast(half8, d);
}

// ---- fast pre-pass (layouts bit-equivalent to the verified R4 prep):
// K planes: out[(bh*S+t)*64 + p*8 + e] = f16( K[bh][t][(p^(t&7))*8 + e] )
// V planes: out[(bh*64+d)*S + w*64 + p*8 + e] =
//             f16( V[bh][ w*64 + ((p&4)|((p&3)^(d&3)))*8 + e ][ d ] )
__global__ __launch_bounds__(256)
void prep_all2(const float* __restrict__ kr, const float* __restrict__ ki,
               const float* __restrict__ vr, const float* __restrict__ vi,
               _Float16* __restrict__ okr, _Float16* __restrict__ oki,
               _Float16* __restrict__ ovr, _Float16* __restrict__ ovi)
{
    const int tid = (int)threadIdx.x;
    const int b   = (int)blockIdx.x;

    if (b < 2048) {
        // ---- K: one 16B output chunk per thread, both planes ----
        const int idx = b * 256 + tid;          // 0 .. 524287
        const int R   = idx >> 3, p = idx & 7;  // R = bh*S + t ; t&7 == R&7
        const int key = R & 7;
        const size_t in = (size_t)R * 64 + (size_t)((p ^ key) * 8);
        const size_t ot = (size_t)idx * 8;
        float4 a0 = *(const float4*)(kr + in);
        float4 a1 = *(const float4*)(kr + in + 4);
        float4 c0 = *(const float4*)(ki + in);
        float4 c1 = *(const float4*)(ki + in + 4);
        uint4_t ha = (uint4_t){pk2(a0.x,a0.y), pk2(a0.z,a0.w),
                               pk2(a1.x,a1.y), pk2(a1.z,a1.w)};
        uint4_t hc = (uint4_t){pk2(c0.x,c0.y), pk2(c0.z,c0.w),
                               pk2(c1.x,c1.y), pk2(c1.z,c1.w)};
        *(uint4_t*)(okr + ot) = ha;
        *(uint4_t*)(oki + ot) = hc;
    } else {
        // ---- V: 8x8 in-register transpose; block = (bh, z, 256-row t-span) ----
        const int b2   = b - 2048;              // 0..511
        const int bh   = b2 >> 4;
        const int rest = b2 & 15;
        const int z    = rest >> 3, Tb = rest & 7;
        const int T    = Tb * 256;
        const float* src = z ? vi : vr;
        _Float16*    dst = z ? ovi : ovr;

        const int tq = tid & 31, dq = tid >> 5;   // 32 t-chunks x 8 d-chunks
        const int t0 = T + tq * 8, d0 = dq * 8;

        float v[8][8];
        #pragma unroll
        for (int i = 0; i < 8; ++i) {
            const size_t in = ((size_t)bh * S + t0 + i) * 64 + d0;
            float4 lo = *(const float4*)(src + in);
            float4 hi = *(const float4*)(src + in + 4);
            v[i][0]=lo.x; v[i][1]=lo.y; v[i][2]=lo.z; v[i][3]=lo.w;
            v[i][4]=hi.x; v[i][5]=hi.y; v[i][6]=hi.z; v[i][7]=hi.w;
        }

        const int jd = tq & 7;                    // data chunk within 64-window
        const size_t rowoff = (size_t)T + (size_t)(tq >> 3) * 64;  // window base
        #pragma unroll
        for (int j = 0; j < 8; ++j) {
            const int d   = d0 + j;               // d&3 == j&3 (d0 % 8 == 0)
            const int pos = (jd & 4) | ((jd & 3) ^ (j & 3));
            uint4_t h = (uint4_t){pk2(v[0][j], v[1][j]), pk2(v[2][j], v[3][j]),
                                  pk2(v[4][j], v[5][j]), pk2(v[6][j], v[7][j])};
            *(uint4_t*)(dst + ((size_t)bh * 64 + d) * S + rowoff + pos * 8) = h;
        }
    }
}

// ---- main: 16x16x32 MFMA flash complex attention, KT=32 double-buffered ----
// QT=128 via 8-wave (512-thread) blocks — each staged K/V tile serves 2x
// the q-rows (staging, barriers, L2 K/V traffic halve per unit work). Per-wave
// compute/routing byte-identical to R7 (the verified 2-buffer loop). Softmax
// stays SCALAR (R2/R3/R6: every packed variant fails structurally).
__global__ __launch_bounds__(512, 4)
void cv_attn_db(const float* __restrict__ qr_g, const float* __restrict__ qi_g,
                const _Float16* __restrict__ kh_r, const _Float16* __restrict__ kh_i,
                const _Float16* __restrict__ vt_r, const _Float16* __restrict__ vt_i,
                float* __restrict__ out)
{
    // 2 bufs x 4 planes x 2048 halves = 32768 B
    __shared__ __align__(16) _Float16 sm[2*4*2048];

    const int tid = (int)threadIdx.x, lane = tid & 63, wv = tid >> 6;  // wv in [0,8)
    const int g = lane >> 4, m = lane & 15;
    // phi(m): swap bit0 <-> bit2 (involution). Used for V row slot placement.
    const int fm = (m & 10) | ((m & 1) << 2) | ((m >> 2) & 1);

    // XCD-aware decode: 512 blocks = 8 xcd x (16 q-tiles x 4 bh-groups)
    const int b   = (int)blockIdx.x;
    const int xcd = b & 7, y = b >> 3;
    const int qt  = y & 15, bh = xcd + 8 * (y >> 4);
    const int q0  = qt * QT;
    const size_t base = (size_t)bh * S * D;

    // ---- Q fragments (row=m, k=g*8+j + kc*32), scaled by 1/T; Qi negated once ----
    half8 aqr[2], aqi[2], aqin[2];
    {
        const size_t qoff = base + (size_t)(q0 + wv*16 + m) * D + g*8;
        #pragma unroll
        for (int kc = 0; kc < 2; ++kc) {
            float4 r0 = *(const float4*)(qr_g + qoff + kc*32);
            float4 r1 = *(const float4*)(qr_g + qoff + kc*32 + 4);
            float4 i0 = *(const float4*)(qi_g + qoff + kc*32);
            float4 i1 = *(const float4*)(qi_g + qoff + kc*32 + 4);
            half8 hr, hi;
            hr[0]=(_Float16)(r0.x*INV_T); hr[1]=(_Float16)(r0.y*INV_T);
            hr[2]=(_Float16)(r0.z*INV_T); hr[3]=(_Float16)(r0.w*INV_T);
            hr[4]=(_Float16)(r1.x*INV_T); hr[5]=(_Float16)(r1.y*INV_T);
            hr[6]=(_Float16)(r1.z*INV_T); hr[7]=(_Float16)(r1.w*INV_T);
            hi[0]=(_Float16)(i0.x*INV_T); hi[1]=(_Float16)(i0.y*INV_T);
            hi[2]=(_Float16)(i0.z*INV_T); hi[3]=(_Float16)(i0.w*INV_T);
            hi[4]=(_Float16)(i1.x*INV_T); hi[5]=(_Float16)(i1.y*INV_T);
            hi[6]=(_Float16)(i1.z*INV_T); hi[7]=(_Float16)(i1.w*INV_T);
            aqr[kc] = hr; aqi[kc] = hi; aqin[kc] = -hi;
        }
    }

    floatx4 Or[4], Oi[4];
    float l_run = 0.f;                       // l for q=m (lane-local under swapped QK^T)
    #pragma unroll
    for (int nt = 0; nt < 4; ++nt) {
        Or[nt] = (floatx4){0.f,0.f,0.f,0.f};
        Oi[nt] = (floatx4){0.f,0.f,0.f,0.f};
    }

    // ---- per-wave staging bases: 8 waves, plane p = wv>>1, half h = wv&1 ----
    // Each wave issues 2 gl_lds per tile (chunks 2h, 2h+1 of its plane).
    const int sp = wv >> 1, sh = wv & 1;
    const int dl  = lane >> 2;
    const int fdl = (dl & 10) | ((dl & 1) << 2) | ((dl >> 2) & 1);  // phi
    const size_t istride = (sp < 2) ? 512 : (size_t)16*S;
    const _Float16* const stage_src =
        ((sp == 0) ? kh_r + (size_t)bh*S*D + lane*8 :
         (sp == 1) ? kh_i + (size_t)bh*S*D + lane*8 :
         (sp == 2) ? vt_r + ((size_t)bh*D + fdl)*S + (lane&3)*8
                   : vt_i + ((size_t)bh*D + fdl)*S + (lane&3)*8)
        + (size_t)(2*sh) * istride;
    const size_t kstep = (sp < 2) ? (size_t)(32*D) : 32;
    _Float16* const stage_dst0 = sm + sp*2048 + sh*1024;

    auto stage = [&](int kt, int bufsel) {
        const _Float16* s = stage_src + (size_t)kt * kstep;
        _Float16* d = stage_dst0 + bufsel * 8192;
        #pragma unroll
        for (int i = 0; i < 2; ++i)
            gl_lds16(s + i*istride, d + i*512);
    };

    // ---- hoisted compute constants ----
    const int kck0 = (g ^ (m & 7)) * 8, kck1 = ((g + 4) ^ (m & 7)) * 8;
    const int vck  = (g ^ (m & 3)) * 8;
    const int vrb0 = fm * 32;
    const int m64  = m * 64;

    auto compute = [&](const _Float16* bs) {
        const _Float16* const Krt = bs;
        const _Float16* const Kit = bs + 2048;
        const _Float16* const Vrt = bs + 4096;
        const _Float16* const Vit = bs + 6144;

        // ---- scores, swapped: Z^T block nt -> lane holds t = 16nt+4g+r, q = m ----
        floatx4 Zr[2], Zi[2];
        __builtin_amdgcn_s_setprio(1);
        #pragma unroll
        for (int nt = 0; nt < 2; ++nt) {
            const int rb = nt*1024 + m64;
            half8 bkr0 = *(const half8*)&Krt[rb + kck0];
            half8 bki0 = *(const half8*)&Kit[rb + kck0];
            half8 bkr1 = *(const half8*)&Krt[rb + kck1];
            half8 bki1 = *(const half8*)&Kit[rb + kck1];
            floatx4 zr = (floatx4){0.f,0.f,0.f,0.f};
            floatx4 zi = (floatx4){0.f,0.f,0.f,0.f};
            zr = MFMA16(bkr0, aqr[0],  zr);
            zr = MFMA16(bki0, aqin[0], zr);
            zr = MFMA16(bkr1, aqr[1],  zr);
            zr = MFMA16(bki1, aqin[1], zr);    // Zr^T = Kr Qr' - Ki Qi'
            zi = MFMA16(bki0, aqr[0],  zi);
            zi = MFMA16(bkr0, aqi[0],  zi);
            zi = MFMA16(bki1, aqr[1],  zi);
            zi = MFMA16(bkr1, aqi[1],  zi);    // Zi^T = Ki Qr' + Kr Qi'
            Zr[nt] = zr; Zi[nt] = zi;
        }
        __builtin_amdgcn_s_setprio(0);

        // ---- max-free softmax: p = exp(|z|)*2^-4; P = p*z/|z| (SCALAR form) ----
        unsigned PkR[4], PkI[4];   // chunk c = nt*2 + pair: pk(t pair) at group g
        #pragma unroll
        for (int nt = 0; nt < 2; ++nt) {
            float wr[4], wi[4];
            #pragma unroll
            for (int r = 0; r < 4; ++r) {
                const float zr = Zr[nt][r], zi = Zi[nt][r];
                const float s2  = fmaf(zr, zr, fmaf(zi, zi, 1e-24f));
                const float inv = __builtin_amdgcn_rsqf(s2);
                const float mag = s2 * inv;
                const float p   = __expf(mag - MBIAS);
                l_run += p;
                const float w = p * inv;
                wr[r] = w * zr; wi[r] = w * zi;
            }
            PkR[nt*2 + 0] = pk2(wr[0], wr[1]);
            PkR[nt*2 + 1] = pk2(wr[2], wr[3]);
            PkI[nt*2 + 0] = pk2(wi[0], wi[1]);
            PkI[nt*2 + 1] = pk2(wi[2], wi[3]);
        }

        // ---- in-register P transpose: A-fragment (q=m, t=8g..8g+7) per plane ----
        half8 apr = xpose4(PkR[0], PkR[1], PkR[2], PkR[3]);
        half8 api = xpose4(PkI[0], PkI[1], PkI[2], PkI[3]);
        half8 nai = -api;

        // ---- PV: O += P * V. Row nt*16+m lives at slot nt*16+phi(m);
        // ---- chunk key (g ^ (m&3)) -> routing identical to R1.
        __builtin_amdgcn_s_setprio(1);
        #pragma unroll
        for (int nt = 0; nt < 4; ++nt) {
            const int vrb = nt*512 + vrb0;
            half8 bvr = *(const half8*)&Vrt[vrb + vck];
            half8 bvi = *(const half8*)&Vit[vrb + vck];
            Or[nt] = MFMA16(apr, bvr, Or[nt]);
            Or[nt] = MFMA16(nai, bvi, Or[nt]);
            Oi[nt] = MFMA16(apr, bvi, Oi[nt]);
            Oi[nt] = MFMA16(api, bvr, Oi[nt]);
        }
        __builtin_amdgcn_s_setprio(0);
    };

    _Float16* const buf0 = sm;
    _Float16* const buf1 = sm + 4*2048;

    stage(0, 0);
    for (int kt = 0; kt < 64; kt += 2) {
        __syncthreads();                    // drains loads into buf0; separates prior compute(buf1)
        stage(kt + 1, 1);
        compute(buf0);
        __syncthreads();                    // drains loads into buf1; separates compute(buf0)
        if (kt < 62) stage(kt + 2, 0);
        compute(buf1);
    }

    // ---- deferred l reduction: sum over the g-quad (each lane has 8 t's per tile) ----
    l_run += __shfl_xor(l_run, 16, 64);
    l_run += __shfl_xor(l_run, 32, 64);
    // lane quad {m,m+16,m+32,m+48} now holds l(q=m); gather l(q=4g+r) for output rows

    #pragma unroll
    for (int r = 0; r < 4; ++r) {
        const float linv = 1.0f / __shfl(l_run, 4*g + r, 64);
        const size_t o = base + (size_t)(q0 + wv*16 + 4*g + r) * D + m;
        #pragma unroll
        for (int nt = 0; nt < 4; ++nt) {
            out[o + nt*16]         = Or[nt][r] * linv;
            out[PLANE + o + nt*16] = Oi[nt][r] * linv;
        }
    }
}

// ---------------- fallback (ws too small): round-2 style, f32 inputs ----------------
constexpr int ST2 = 72;
__global__ __launch_bounds__(256, 2)
void cv_attn_mfma(const float* __restrict__ qr_g, const float* __restrict__ qi_g,
                  const float* __restrict__ kr_g, const float* __restrict__ ki_g,
                  const float* __restrict__ vr_g, const float* __restrict__ vi_g,
                  float* __restrict__ out)
{
    __shared__ __align__(16) _Float16 sm[4*64*ST2 + 4*2*16*ST2];
    _Float16* const Kr = sm;
    _Float16* const Ki = Kr + 64*ST2;
    _Float16* const Vr = Ki + 64*ST2;
    _Float16* const Vi = Vr + 64*ST2;
    _Float16* const Pb = Vi + 64*ST2;

    const int tid = (int)threadIdx.x, lane = tid & 63, wv = tid >> 6;
    const int g = lane >> 4, m = lane & 15;
    const int bh = (int)blockIdx.y;
    const int q0 = (int)blockIdx.x * 64;
    const size_t base = (size_t)bh * S * D;
    _Float16* const Pr = Pb + wv * (2*16*ST2);
    _Float16* const Pi = Pr + 16*ST2;
    const int lofs = m*ST2 + g*8;

    half8 aqr[2], aqi[2], aqin[2];
    {
        const size_t qoff = base + (size_t)(q0 + wv*16 + m) * D + g*8;
        #pragma unroll
        for (int kc = 0; kc < 2; ++kc) {
            float4 r0 = *(const float4*)(qr_g + qoff + kc*32);
            float4 r1 = *(const float4*)(qr_g + qoff + kc*32 + 4);
            float4 i0 = *(const float4*)(qi_g + qoff + kc*32);
            float4 i1 = *(const float4*)(qi_g + qoff + kc*32 + 4);
            half8 hr, hi;
            hr[0]=(_Float16)(r0.x*INV_T); hr[1]=(_Float16)(r0.y*INV_T);
            hr[2]=(_Float16)(r0.z*INV_T); hr[3]=(_Float16)(r0.w*INV_T);
            hr[4]=(_Float16)(r1.x*INV_T); hr[5]=(_Float16)(r1.y*INV_T);
            hr[6]=(_Float16)(r1.z*INV_T); hr[7]=(_Float16)(r1.w*INV_T);
            hi[0]=(_Float16)(i0.x*INV_T); hi[1]=(_Float16)(i0.y*INV_T);
            hi[2]=(_Float16)(i0.z*INV_T); hi[3]=(_Float16)(i0.w*INV_T);
            hi[4]=(_Float16)(i1.x*INV_T); hi[5]=(_Float16)(i1.y*INV_T);
            hi[6]=(_Float16)(i1.z*INV_T); hi[7]=(_Float16)(i1.w*INV_T);
            aqr[kc] = hr; aqi[kc] = hi; aqin[kc] = -hi;
        }
    }

    floatx4 Or[4], Oi[4];
    float m_run[4], l_run[4];
    #pragma unroll
    for (int r = 0; r < 4; ++r) { m_run[r] = -INFINITY; l_run[r] = 0.f; }
    #pragma unroll
    for (int nt = 0; nt < 4; ++nt) {
        Or[nt] = (floatx4){0.f,0.f,0.f,0.f};
        Oi[nt] = (floatx4){0.f,0.f,0.f,0.f};
    }

    for (int kt = 0; kt < S/64; ++kt) {
        const int k0 = kt * 64;
        __syncthreads();
        if (wv < 2) {
            const float* src = (wv == 0 ? kr_g : ki_g) + base + (size_t)k0 * D;
            _Float16* dst = (wv == 0 ? Kr : Ki);
            #pragma unroll
            for (int it = 0; it < 16; ++it) {
                const int e = it*64 + lane, t = e >> 4, c4 = (e & 15) * 4;
                float4 v = *(const float4*)(src + t*64 + c4);
                half4_t hh = {(_Float16)v.x, (_Float16)v.y, (_Float16)v.z, (_Float16)v.w};
                *(half4_t*)&dst[t*ST2 + c4] = hh;
            }
        } else {
            const float* src = (wv == 2 ? vr_g : vi_g) + base + (size_t)k0 * D;
            _Float16* dst = (wv == 2 ? Vr : Vi);
            #pragma unroll
            for (int t0 = 0; t0 < 64; t0 += 4) {
                float v0 = src[(t0+0)*64 + lane];
                float v1 = src[(t0+1)*64 + lane];
                float v2 = src[(t0+2)*64 + lane];
                float v3 = src[(t0+3)*64 + lane];
                half4_t hh = {(_Float16)v0, (_Float16)v1, (_Float16)v2, (_Float16)v3};
                *(half4_t*)&dst[lane*ST2 + t0] = hh;
            }
        }
        __syncthreads();

        floatx4 Zr[4], Zi[4];
        #pragma unroll
        for (int nt = 0; nt < 4; ++nt) {
            floatx4 zr = (floatx4){0.f,0.f,0.f,0.f};
            floatx4 zi = (floatx4){0.f,0.f,0.f,0.f};
            #pragma unroll
            for (int kc = 0; kc < 2; ++kc) {
                const int o = nt*16*ST2 + lofs + kc*32;
                half8 bkr = *(const half8*)&Kr[o];
                half8 bki = *(const half8*)&Ki[o];
                zr = MFMA16(aqr[kc],  bkr, zr);
                zr = MFMA16(aqin[kc], bki, zr);
                zi = MFMA16(aqr[kc],  bki, zi);
                zi = MFMA16(aqi[kc],  bkr, zi);
            }
            Zr[nt] = zr; Zi[nt] = zi;
        }

        float mag[4][4], mt[4] = {0.f,0.f,0.f,0.f};
        #pragma unroll
        for (int nt = 0; nt < 4; ++nt)
            #pragma unroll
            for (int r = 0; r < 4; ++r) {
                const float a = Zr[nt][r], bz = Zi[nt][r];
                const float s = __builtin_amdgcn_sqrtf(a*a + bz*bz);
                mag[nt][r] = s; mt[r] = fmaxf(mt[r], s);
            }
        #pragma unroll
        for (int off = 1; off < 16; off <<= 1)
            #pragma unroll
            for (int r = 0; r < 4; ++r)
                mt[r] = fmaxf(mt[r], __shfl_xor(mt[r], off, 64));

        float alpha[4], rs[4];
        #pragma unroll
        for (int r = 0; r < 4; ++r) {
            const float mnew = fmaxf(m_run[r], mt[r]);
            alpha[r] = __expf(m_run[r] - mnew);
            m_run[r] = mnew; rs[r] = 0.f;
        }
        #pragma unroll
        for (int nt = 0; nt < 4; ++nt)
            #pragma unroll
            for (int r = 0; r < 4; ++r) {
                const float p = __expf(mag[nt][r] - m_run[r]);
                rs[r] += p;
                const float w = p * __builtin_amdgcn_rcpf(fmaxf(mag[nt][r], 1e-12f));
                Pr[(4*g + r)*ST2 + nt*16 + m] = (_Float16)(w * Zr[nt][r]);
                Pi[(4*g + r)*ST2 + nt*16 + m] = (_Float16)(w * Zi[nt][r]);
            }
        #pragma unroll
        for (int off = 1; off < 16; off <<= 1)
            #pragma unroll
            for (int r = 0; r < 4; ++r)
                rs[r] += __shfl_xor(rs[r], off, 64);
        #pragma unroll
        for (int r = 0; r < 4; ++r) l_run[r] = l_run[r]*alpha[r] + rs[r];

        #pragma unroll
        for (int nt = 0; nt < 4; ++nt)
            #pragma unroll
            for (int r = 0; r < 4; ++r) { Or[nt][r] *= alpha[r]; Oi[nt][r] *= alpha[r]; }

        half8 apr[2], api[2], apin[2];
        #pragma unroll
        for (int kc = 0; kc < 2; ++kc) {
            apr[kc]  = *(const half8*)&Pr[lofs + kc*32];
            api[kc]  = *(const half8*)&Pi[lofs + kc*32];
            apin[kc] = -api[kc];
        }
        #pragma unroll
        for (int nt = 0; nt < 4; ++nt) {
            floatx4 ors = Or[nt], ois = Oi[nt];
            #pragma unroll
            for (int kc = 0; kc < 2; ++kc) {
                const int o = nt*16*ST2 + lofs + kc*32;
                half8 bvr = *(const half8*)&Vr[o];
                half8 bvi = *(const half8*)&Vi[o];
                ors = MFMA16(apr[kc],  bvr, ors);
                ors = MFMA16(apin[kc], bvi, ors);
                ois = MFMA16(apr[kc],  bvi, ois);
                ois = MFMA16(api[kc],  bvr, ois);
            }
            Or[nt] = ors; Oi[nt] = ois;
        }
    }

    #pragma unroll
    for (int r = 0; r < 4; ++r) {
        const float linv = 1.0f / l_run[r];
        const size_t o = base + (size_t)(q0 + wv*16 + 4*g + r) * D + m;
        #pragma unroll
        for (int nt = 0; nt < 4; ++nt) {
            out[o + nt*16]         = Or[nt][r] * linv;
            out[PLANE + o + nt*16] = Oi[nt][r] * linv;
        }
    }
}

} // namespace

extern "C" void kernel_launch(void* const* d_in, const int* in_sizes, int n_in,
                              void* d_out, int out_size, void* d_ws, size_t ws_size,
                              hipStream_t stream) {
    const float* qr = (const float*)d_in[0];
    const float* qi = (const float*)d_in[1];
    const float* kr = (const float*)d_in[2];
    const float* ki = (const float*)d_in[3];
    const float* vr = (const float*)d_in[4];
    const float* vi = (const float*)d_in[5];
    float* out = (float*)d_out;

    const size_t PH = (size_t)BH * S * D;            // halves per ws plane
    const size_t need = 4 * PH * sizeof(_Float16);   // 33.6 MB
    if (ws_size >= need) {
        _Float16* khr = (_Float16*)d_ws;
        _Float16* khi = khr + PH;
        _Float16* vtr = khi + PH;
        _Float16* vti = vtr + PH;
        prep_all2<<<2560, 256, 0, stream>>>(kr, ki, vr, vi, khr, khi, vtr, vti);
        cv_attn_db<<<512, 512, 0, stream>>>(qr, qi, khr, khi, vtr, vti, out);
    } else {
        cv_attn_mfma<<<dim3(32, 32), 256, 0, stream>>>(qr, qi, kr, ki, vr, vi, out);
    }
}